// Round 3
// baseline (5468.556 us; speedup 1.0000x reference)
//
#include <hip/hip_runtime.h>
#include <hip/hip_fp16.h>

// Problem constants
#define TSTEPS 1024
#define HDIM   1024
#define INDIM  512
#define NGATE  4096     // 4*HDIM
#define NWG    192      // proven-launchable coop envelope (R11)
#define POISON_U 0x7C7C7C7Cu   // ~5.2e36 as f32: unreachable for |h|<1 or gate sums
#define SPIN_MAX (1 << 20)     // deadlock valve: fail loud, never hang

// ---------------------------------------------------------------------------
// R12 post-mortem: sc0 (SE-scope) polls never saw the stores (stale lines ->
// every poll popped its valve -> NaN, ~220s run). R13: revert to the PROVEN
// agent-scope poison-poll protocol (R11), keep only the safe structural wins:
//   * 3 pipelined layer stages (64 WGs each, 192 total = proven coop grid).
//     Each layer polls its own h row + its input h row CONCURRENTLY in one
//     spin loop -> 1 LLC round trip per step instead of 3 serialized.
//   * LDS row staging (R11 pattern) keeps poll traffic ~1.25 MB/step.
//   * f16 weights resident in VGPRs (64 uints/lane); dot via
//     fmaf((float)h16,(float)w16,acc) -> v_fma_mix_f32 (no unpack instrs).
//   * DPP wave reduction (VALU pipe) instead of ds_swizzle shuffles.
// R14: fix cvt_pkrtz return-type mismatch (auto + bit_cast). No other change.
// ---------------------------------------------------------------------------

typedef unsigned uint4v __attribute__((ext_vector_type(4)));
typedef _Float16 half2v __attribute__((ext_vector_type(2)));

#define PIN4(v) asm volatile("" : "+v"(v))

__device__ __forceinline__ half2v as_h2(unsigned u) {
    return __builtin_bit_cast(half2v, u);
}

// 2-term f16->f32 fma pair; backend fuses (fpext+fpext+fma) into v_fma_mix_f32.
__device__ __forceinline__ float dot2f(unsigned h, unsigned w, float c) {
    half2v a = as_h2(h), b = as_h2(w);
    c = fmaf((float)a[0], (float)b[0], c);
    c = fmaf((float)a[1], (float)b[1], c);
    return c;
}

__device__ __forceinline__ float dot8(uint4v hA, uint4v hB,
                                      uint4v wA, uint4v wB, float c) {
    c = dot2f(hA.x, wA.x, c);
    c = dot2f(hA.y, wA.y, c);
    c = dot2f(hA.z, wA.z, c);
    c = dot2f(hA.w, wA.w, c);
    c = dot2f(hB.x, wB.x, c);
    c = dot2f(hB.y, wB.y, c);
    c = dot2f(hB.z, wB.z, c);
    c = dot2f(hB.w, wB.w, c);
    return c;
}

// Full-wave sum via DPP adds (VALU pipe). Canonical GCN sequence:
// row_shr 1,2,4,8 then row_bcast15 (rows 1,3) + row_bcast31 (rows 2,3).
// Result valid in lane 63 (where the activation runs). old=0 => masked /
// invalid source lanes contribute 0.
__device__ __forceinline__ float wave_sum64_dpp(float v) {
    int x;
    x = __builtin_amdgcn_update_dpp(0, __float_as_int(v), 0x111, 0xf, 0xf, false); v += __int_as_float(x);
    x = __builtin_amdgcn_update_dpp(0, __float_as_int(v), 0x112, 0xf, 0xf, false); v += __int_as_float(x);
    x = __builtin_amdgcn_update_dpp(0, __float_as_int(v), 0x114, 0xf, 0xf, false); v += __int_as_float(x);
    x = __builtin_amdgcn_update_dpp(0, __float_as_int(v), 0x118, 0xf, 0xf, false); v += __int_as_float(x);
    x = __builtin_amdgcn_update_dpp(0, __float_as_int(v), 0x142, 0xa, 0xf, false); v += __int_as_float(x);
    x = __builtin_amdgcn_update_dpp(0, __float_as_int(v), 0x143, 0xc, 0xf, false); v += __int_as_float(x);
    return v;
}

__device__ __forceinline__ float sigm(float x) { return 1.f / (1.f + __expf(-x)); }
__device__ __forceinline__ float fast_tanh(float x) {
    float t = __expf(-2.f * fabsf(x));
    float r = (1.f - t) / (1.f + t);
    return copysignf(r, x);
}

// single-instruction f32 pair -> packed f16 (v_cvt_pkrtz_f16_f32).
// NOTE: builtin returns __fp16-vector, not _Float16-vector -> take it as auto
// and bit_cast to unsigned (R13 compile fix).
__device__ __forceinline__ unsigned pack_h(float a, float b) {
    auto p = __builtin_amdgcn_cvt_pkrtz(a, b);
    return __builtin_bit_cast(unsigned, p);
}

__device__ __forceinline__ float agent_loadf(const float* p) {
    return __hip_atomic_load(const_cast<float*>(p), __ATOMIC_RELAXED,
                             __HIP_MEMORY_SCOPE_AGENT);
}
__device__ __forceinline__ void agent_storef(float* p, float v) {
    __hip_atomic_store(p, v, __ATOMIC_RELAXED, __HIP_MEMORY_SCOPE_AGENT);
}
__device__ __forceinline__ bool isp(float v) { return __float_as_uint(v) == POISON_U; }

// ---------------------------------------------------------------------------
// Prep: pack fp32 matrix (rows x 1024) into f16-pair uints (rows x 512), RNE.
// dst[i] = f16(col 2i) | f16(col 2i+1)<<16.
// ---------------------------------------------------------------------------
__global__ __launch_bounds__(256) void pack_f16(
    const float* __restrict__ src, unsigned* __restrict__ dst, int n)
{
    int i = blockIdx.x * 256 + threadIdx.x;
    if (i < n) {
        float2 v = *(const float2*)(src + 2 * (size_t)i);
        dst[i] = (unsigned)__half_as_ushort(__float2half(v.x)) |
                 ((unsigned)__half_as_ushort(__float2half(v.y)) << 16);
    }
}

// ---------------------------------------------------------------------------
// GEMM for layer-1 input gates: G[t][n] = concat(x,time)[t] . Wih1[n] + b.
// (fp32, one-shot before the scan — unchanged, proven)
// ---------------------------------------------------------------------------
#define BM 64
#define BN 64
#define BK 32

__global__ __launch_bounds__(256) void gemm_tn(
    const float* __restrict__ B,
    const float* __restrict__ bias1,
    const float* __restrict__ bias2,
    float* __restrict__ C,
    int M, int N, int K,
    const float* __restrict__ x,
    const float* __restrict__ timev)
{
    __shared__ float As[BK][BM + 4];
    __shared__ float Bs[BK][BN + 4];

    const int tid = threadIdx.x;
    const int mblocks = M / BM;
    const int bm = blockIdx.x % mblocks;
    const int bn = blockIdx.x / mblocks;
    const int t0 = bm * BM;
    const int n0 = bn * BN;

    const int tx = tid & 15;
    const int ty = tid >> 4;

    float acc[4][4] = {{0.f}};

    for (int kc = 0; kc < K; kc += BK) {
#pragma unroll
        for (int i = 0; i < 8; i++) {
            int idx = tid + i * 256;
            int r = idx >> 5;
            int c = idx & 31;
            int col = kc + c;
            int trow = t0 + r;
            float av = (col < INDIM) ? x[(size_t)trow * INDIM + col]
                                     : ((col == INDIM) ? timev[trow] : 0.f);
            As[c][r] = av;
            int nrow = n0 + r;
            Bs[c][r] = (col < K) ? B[(size_t)nrow * K + col] : 0.f;
        }
        __syncthreads();

#pragma unroll
        for (int kk = 0; kk < BK; kk++) {
            float a[4], b[4];
#pragma unroll
            for (int i = 0; i < 4; i++) a[i] = As[kk][ty * 4 + i];
#pragma unroll
            for (int j = 0; j < 4; j++) b[j] = Bs[kk][tx * 4 + j];
#pragma unroll
            for (int i = 0; i < 4; i++)
#pragma unroll
                for (int j = 0; j < 4; j++)
                    acc[i][j] = fmaf(a[i], b[j], acc[i][j]);
        }
        __syncthreads();
    }

#pragma unroll
    for (int i = 0; i < 4; i++) {
        int trow = t0 + ty * 4 + i;
#pragma unroll
        for (int j = 0; j < 4; j++) {
            int n = n0 + tx * 4 + j;
            C[(size_t)trow * N + n] = acc[i][j] + bias1[n] + bias2[n];
        }
    }
}

// ---------------------------------------------------------------------------
// Fused 3-layer scan, layer-pipelined.
// role = blockIdx/64 (0=L1, 1=L2, 2=L3), slot = blockIdx%64.
// Wave q of WG slot owns unit u = slot*16 + q (1 unit, all 4 gates).
// Per step: threads 0..511 poll+pack the recurrent row h_L[t-1], threads
// 512..1023 poll+pack the input row (h1[t] for L2, h2[t] for L3) -> LDS ->
// barrier -> per-wave dots + DPP reduce -> lane63 activation -> agent store.
// All h rows fp32, poison-initialized; the poll IS the data load.
// ---------------------------------------------------------------------------
__global__ __launch_bounds__(1024, 4) void fused_scan(
    const unsigned* __restrict__ Wp1,     // packed Whh1, 4096 x 512
    const unsigned* __restrict__ Wpi2,    // packed Wih2
    const unsigned* __restrict__ Wph2,    // packed Whh2
    const float* __restrict__ G1,         // layer-1 input gates (+biases)
    const float* bih2, const float* bhh2,
    const float* h0_1, const float* c0_1,
    const float* h0_2, const float* c0_2,
    const float* h0_3, const float* c0_3,
    float* H1f, float* H2f, float* H3f)   // fp32 h rows, poisoned
{
    const int tid  = threadIdx.x;
    const int q    = tid >> 6;      // wave 0..15
    const int l    = tid & 63;
    const int role = blockIdx.x >> 6;   // 0,1,2
    const int slot = blockIdx.x & 63;
    const int u    = slot * 16 + q;

    __shared__ unsigned shrc[512] __attribute__((aligned(16)));  // packed rec row
    __shared__ unsigned shin[512] __attribute__((aligned(16)));  // packed input row

    const float* Hin  = (role == 2) ? H2f : H1f;   // input row source (role>=1)
    float* Hrec = (role == 0) ? H1f : (role == 1) ? H2f : H3f;
    const float* h0r = (role == 0) ? h0_1 : (role == 1) ? h0_2 : h0_3;
    const float* c0r = (role == 0) ? c0_1 : (role == 1) ? c0_2 : c0_3;

    // resident f16 weights: gate g row = g*1024 + u
    uint4v whA[4], whB[4], wiA[4], wiB[4];
    const unsigned* Wrec = (role == 0) ? Wp1 : Wph2;
#pragma unroll
    for (int g = 0; g < 4; ++g) {
        const uint4v* ph = (const uint4v*)(Wrec + (size_t)((g << 10) + u) * 512);
        whA[g] = ph[l];
        whB[g] = ph[64 + l];
    }
    if (role) {
#pragma unroll
        for (int g = 0; g < 4; ++g) {
            const uint4v* pi = (const uint4v*)(Wpi2 + (size_t)((g << 10) + u) * 512);
            wiA[g] = pi[l];
            wiB[g] = pi[64 + l];
        }
    } else {
#pragma unroll
        for (int g = 0; g < 4; ++g) {
            wiA[g] = uint4v{0u, 0u, 0u, 0u};
            wiB[g] = uint4v{0u, 0u, 0u, 0u};
        }
    }

    float cs = 0.f, b0 = 0.f, b1 = 0.f, b2 = 0.f, b3 = 0.f;
    if (l == 63) {
        cs = c0r[u];
        if (role) {
            b0 = bih2[u]        + bhh2[u];
            b1 = bih2[1024 + u] + bhh2[1024 + u];
            b2 = bih2[2048 + u] + bhh2[2048 + u];
            b3 = bih2[3072 + u] + bhh2[3072 + u];
        }
    }

    const int  sid       = tid & 511;       // packed uint this thread produces
    const bool stage_rec = (tid < 512);

    for (int t = 0; t < TSTEPS; ++t) {
        // keep resident weights live (zero instructions)
#pragma unroll
        for (int g = 0; g < 4; ++g) {
            PIN4(whA[g]); PIN4(whB[g]); PIN4(wiA[g]); PIN4(wiB[g]);
        }

        // L1 gate-input prefetch (precomputed, plain cached loads); consumed
        // after the reduce, so its latency hides under staging + dots.
        float g0 = 0.f, g1v = 0.f, g2 = 0.f, g3 = 0.f;
        if (role == 0 && l == 63) {
            const float* gp = G1 + (size_t)t * NGATE + u;
            g0  = gp[0];
            g1v = gp[1024];
            g2  = gp[2048];
            g3  = gp[3072];
        }

        // ---- stage: poll 2 fp32, pack, write LDS ----
        if (stage_rec) {
            if (t == 0) {
                shrc[sid] = pack_h(h0r[2 * sid], h0r[2 * sid + 1]);
            } else {
                const float* p = Hrec + (size_t)(t - 1) * HDIM + 2 * sid;
                float a = 0.f, b = 0.f;
                for (int it = 0; it < SPIN_MAX; ++it) {
                    a = agent_loadf(p);
                    b = agent_loadf(p + 1);
                    if (__ballot(isp(a) | isp(b)) == 0ULL) break;
                    __builtin_amdgcn_s_sleep(1);
                }
                shrc[sid] = pack_h(a, b);
            }
        } else if (role) {
            const float* p = Hin + (size_t)t * HDIM + 2 * sid;
            float a = 0.f, b = 0.f;
            for (int it = 0; it < SPIN_MAX; ++it) {
                a = agent_loadf(p);
                b = agent_loadf(p + 1);
                if (__ballot(isp(a) | isp(b)) == 0ULL) break;
                __builtin_amdgcn_s_sleep(1);
            }
            shin[sid] = pack_h(a, b);
        }
        __syncthreads();                                   // A: rows staged

        // fragments: lane l covers cols 8l..8l+7 and 512+8l..512+8l+7
        uint4v rA = *(const uint4v*)&shrc[4 * l];
        uint4v rB = *(const uint4v*)&shrc[256 + 4 * l];
        uint4v iA = uint4v{0u, 0u, 0u, 0u}, iB = iA;
        if (role) {
            iA = *(const uint4v*)&shin[4 * l];
            iB = *(const uint4v*)&shin[256 + 4 * l];
        }
        __syncthreads();                                   // B: LDS reusable

        float a0 = dot8(rA, rB, whA[0], whB[0], 0.f);
        float a1 = dot8(rA, rB, whA[1], whB[1], 0.f);
        float a2 = dot8(rA, rB, whA[2], whB[2], 0.f);
        float a3 = dot8(rA, rB, whA[3], whB[3], 0.f);
        if (role) {
            a0 = dot8(iA, iB, wiA[0], wiB[0], a0);
            a1 = dot8(iA, iB, wiA[1], wiB[1], a1);
            a2 = dot8(iA, iB, wiA[2], wiB[2], a2);
            a3 = dot8(iA, iB, wiA[3], wiB[3], a3);
        }
        float sg0 = wave_sum64_dpp(a0);
        float sg1 = wave_sum64_dpp(a1);
        float sg2 = wave_sum64_dpp(a2);
        float sg3 = wave_sum64_dpp(a3);

        if (l == 63) {
            float gi, gf, gg, go;
            if (role == 0) { gi = sg0 + g0; gf = sg1 + g1v; gg = sg2 + g2; go = sg3 + g3; }
            else           { gi = sg0 + b0; gf = sg1 + b1;  gg = sg2 + b2; go = sg3 + b3; }
            float i_ = sigm(gi), f_ = sigm(gf), g_ = fast_tanh(gg), o_ = sigm(go);
            cs = f_ * cs + i_ * g_;
            float hn = o_ * fast_tanh(cs);
            agent_storef(Hrec + (size_t)t * HDIM + u, hn);
        }
        // no drain, no flag: the stored dwords ARE the signal
    }
}

// ---------------------------------------------------------------------------
// Attention (unchanged, proven)
// ---------------------------------------------------------------------------
__global__ __launch_bounds__(256) void attn_dot(
    const float* __restrict__ H3, float* __restrict__ attn)
{
    const int t = blockIdx.x * 4 + (threadIdx.x >> 6);
    const int lane = threadIdx.x & 63;
    const float* hrow = H3 + (size_t)t * HDIM;
    const float* hf = H3 + (size_t)(TSTEPS - 1) * HDIM;
    float p = 0.f;
    for (int j = lane; j < HDIM; j += 64) p = fmaf(hrow[j], hf[j], p);
#pragma unroll
    for (int d = 32; d; d >>= 1) p += __shfl_down(p, d, 64);
    if (lane == 0) attn[t] = p;
}

__global__ __launch_bounds__(64) void softmax_1024(float* attn)
{
    const int lane = threadIdx.x;
    float vals[16];
    float m = -1e30f;
#pragma unroll
    for (int i = 0; i < 16; i++) {
        vals[i] = attn[lane + i * 64];
        m = fmaxf(m, vals[i]);
    }
#pragma unroll
    for (int d = 32; d; d >>= 1) m = fmaxf(m, __shfl_xor(m, d, 64));
    float s = 0.f;
#pragma unroll
    for (int i = 0; i < 16; i++) {
        vals[i] = expf(vals[i] - m);
        s += vals[i];
    }
#pragma unroll
    for (int d = 32; d; d >>= 1) s += __shfl_xor(s, d, 64);
    float inv = 1.f / s;
#pragma unroll
    for (int i = 0; i < 16; i++) attn[lane + i * 64] = vals[i] * inv;
}

__global__ __launch_bounds__(256) void context_kernel(
    const float* __restrict__ H3, const float* __restrict__ w,
    float* __restrict__ out)
{
    const int u = blockIdx.x * 4 + (threadIdx.x >> 6);
    const int lane = threadIdx.x & 63;
    float p = 0.f;
    for (int t = lane; t < TSTEPS; t += 64)
        p = fmaf(H3[(size_t)t * HDIM + u], w[t], p);
#pragma unroll
    for (int d = 32; d; d >>= 1) p += __shfl_down(p, d, 64);
    if (lane == 0) out[u] = p;
}

// ---------------------------------------------------------------------------
// Launch
// ---------------------------------------------------------------------------
extern "C" void kernel_launch(void* const* d_in, const int* in_sizes, int n_in,
                              void* d_out, int out_size, void* d_ws, size_t ws_size,
                              hipStream_t stream)
{
    const float* x     = (const float*)d_in[0];
    const float* timev = (const float*)d_in[1];
    const float* h0_1  = (const float*)d_in[2];
    const float* c0_1  = (const float*)d_in[3];
    const float* h0_2  = (const float*)d_in[4];
    const float* c0_2  = (const float*)d_in[5];
    const float* h0_3  = (const float*)d_in[6];
    const float* c0_3  = (const float*)d_in[7];
    const float* Wih1  = (const float*)d_in[8];
    const float* Whh1  = (const float*)d_in[9];
    const float* bih1  = (const float*)d_in[10];
    const float* bhh1  = (const float*)d_in[11];
    const float* Wih2  = (const float*)d_in[12];
    const float* Whh2  = (const float*)d_in[13];
    const float* bih2  = (const float*)d_in[14];
    const float* bhh2  = (const float*)d_in[15];

    // workspace carve (~52 MB)
    float* G1v  = (float*)d_ws;                          // 1024*4096 fp32
    float* H1f  = G1v + (size_t)TSTEPS * NGATE;          // 1024*1024 fp32
    float* H2f  = H1f + (size_t)TSTEPS * HDIM;
    float* H3f  = H2f + (size_t)TSTEPS * HDIM;
    float* attn = H3f + (size_t)TSTEPS * HDIM;           // 1024 fp32
    unsigned* Wp1  = (unsigned*)(attn + 1024);           // 4096*512 uints each
    unsigned* Wpi2 = Wp1 + (size_t)NGATE * 512;
    unsigned* Wph2 = Wpi2 + (size_t)NGATE * 512;
    float* out  = (float*)d_out;

    // Poison H1f..H3f (contiguous): the data-poll protocol depends on it.
    hipMemsetAsync(H1f, 0x7C, (size_t)3 * TSTEPS * HDIM * sizeof(float), stream);

    // Pack the three scan weight matrices to f16 pairs (one-time).
    {
        const int n = NGATE * 512;
        pack_f16<<<dim3(n / 256), dim3(256), 0, stream>>>(Whh1, Wp1, n);
        pack_f16<<<dim3(n / 256), dim3(256), 0, stream>>>(Wih2, Wpi2, n);
        pack_f16<<<dim3(n / 256), dim3(256), 0, stream>>>(Whh2, Wph2, n);
    }

    // Layer-1 input gates: G = concat(x,time) @ Wih1^T + bih1 + bhh1 (fp32)
    gemm_tn<<<dim3(1024), dim3(256), 0, stream>>>(Wih1, bih1, bhh1, G1v,
                                                  TSTEPS, NGATE, INDIM + 1,
                                                  x, timev);

    // Fused layer-pipelined scan (cooperative: 192 WGs x 1024 threads)
    {
        const unsigned* a0 = Wp1;  const unsigned* a1 = Wpi2;
        const unsigned* a2 = Wph2; const float* a3 = G1v;
        const float* a4 = bih2;    const float* a5 = bhh2;
        const float* a6 = h0_1;    const float* a7 = c0_1;
        const float* a8 = h0_2;    const float* a9 = c0_2;
        const float* a10 = h0_3;   const float* a11 = c0_3;
        float* a12 = H1f; float* a13 = H2f; float* a14 = H3f;
        void* args[] = {&a0,&a1,&a2,&a3,&a4,&a5,&a6,&a7,&a8,&a9,&a10,&a11,
                        &a12,&a13,&a14};
        hipLaunchCooperativeKernel((void*)fused_scan, dim3(NWG), dim3(1024),
                                   args, 0, stream);
    }

    // Attention
    attn_dot<<<dim3(256), dim3(256), 0, stream>>>(H3f, attn);
    softmax_1024<<<dim3(1), dim3(64), 0, stream>>>(attn);
    context_kernel<<<dim3(256), dim3(256), 0, stream>>>(H3f, attn, out);
}

// Round 4
// 3841.173 us; speedup vs baseline: 1.4237x; 1.4237x over previous
//
#include <hip/hip_runtime.h>
#include <hip/hip_fp16.h>

// Problem constants
#define TSTEPS 1024
#define HDIM   1024
#define INDIM  512
#define NGATE  4096     // 4*HDIM
#define NWG_L1  64
#define NWG_L23 128
#define NWG_TOT 192     // proven coop envelope
#define POISON_U 0x7C7C7C7Cu   // ~5.2e36 as f32: unreachable for |h|<1 or gate sums
#define SPIN_MAX (1 << 20)     // deadlock valve: fail loud, never hang

// ---------------------------------------------------------------------------
// R14 post-mortem: per-wave 4B agent stores caused 8x write amplification
// (WRITE_SIZE 12->98 MB) and a longer store->visible tail -> 5.17 us/step
// (WORSE than R11's 3.86). R15: exact R11 structure (64 L1 WGs + 128 L23 WGs,
// LDS gbuf + coalesced tid<16 activation/store) with only the validated cuts:
//   * L23: ONE combined spin loop for h1[t], h2[t-1], h3[t-2] (R11 ran three
//     sequential spin loops -> ~2 extra LLC RTs/step).
//   * DPP wave reduction (VALU pipe; R14-validated) instead of 24 serialized
//     ds_swizzle shuffles per step.
//   * f16 weights resident in VGPRs, h kept fp32 in LDS, dot via
//     fmaf(h_f32, (float)w_f16, acc) -> v_fma_mix (R14-validated numerics).
// Store/poll protocol is byte-identical to R11 (agent-scope, poison-poll).
// ---------------------------------------------------------------------------

typedef _Float16 half2v __attribute__((ext_vector_type(2)));

#define PINU(v) asm volatile("" : "+v"(v))

// fp32 h x packed-f16 weight pair; backend folds fpext+fma into v_fma_mix.
__device__ __forceinline__ float mix2(float2 h, unsigned w, float c) {
    half2v ww = __builtin_bit_cast(half2v, w);
    c = fmaf(h.x, (float)ww[0], c);
    c = fmaf(h.y, (float)ww[1], c);
    return c;
}

// Full-wave sum via DPP adds (VALU pipe; validated in R14). Result valid in
// lane 63. row_shr 1,2,4,8 then row_bcast15 (rows 1,3) + row_bcast31 (rows 2,3).
__device__ __forceinline__ float wave_sum64_dpp(float v) {
    int x;
    x = __builtin_amdgcn_update_dpp(0, __float_as_int(v), 0x111, 0xf, 0xf, false); v += __int_as_float(x);
    x = __builtin_amdgcn_update_dpp(0, __float_as_int(v), 0x112, 0xf, 0xf, false); v += __int_as_float(x);
    x = __builtin_amdgcn_update_dpp(0, __float_as_int(v), 0x114, 0xf, 0xf, false); v += __int_as_float(x);
    x = __builtin_amdgcn_update_dpp(0, __float_as_int(v), 0x118, 0xf, 0xf, false); v += __int_as_float(x);
    x = __builtin_amdgcn_update_dpp(0, __float_as_int(v), 0x142, 0xa, 0xf, false); v += __int_as_float(x);
    x = __builtin_amdgcn_update_dpp(0, __float_as_int(v), 0x143, 0xc, 0xf, false); v += __int_as_float(x);
    return v;
}

__device__ __forceinline__ float sigm(float x) { return 1.f / (1.f + __expf(-x)); }
__device__ __forceinline__ float fast_tanh(float x) {
    float t = __expf(-2.f * fabsf(x));
    float r = (1.f - t) / (1.f + t);
    return copysignf(r, x);
}

__device__ __forceinline__ float agent_loadf(const float* p) {
    return __hip_atomic_load(const_cast<float*>(p), __ATOMIC_RELAXED,
                             __HIP_MEMORY_SCOPE_AGENT);
}
__device__ __forceinline__ void agent_storef(float* p, float v) {
    __hip_atomic_store(p, v, __ATOMIC_RELAXED, __HIP_MEMORY_SCOPE_AGENT);
}
__device__ __forceinline__ bool isp(float v) { return __float_as_uint(v) == POISON_U; }

// ---------------------------------------------------------------------------
// Prep: pack fp32 matrix (rows x 1024) into f16-pair uints (rows x 512), RNE.
// dst[i] = f16(col 2i) | f16(col 2i+1)<<16.
// ---------------------------------------------------------------------------
__global__ __launch_bounds__(256) void pack_f16(
    const float* __restrict__ src, unsigned* __restrict__ dst, int n)
{
    int i = blockIdx.x * 256 + threadIdx.x;
    if (i < n) {
        float2 v = *(const float2*)(src + 2 * (size_t)i);
        dst[i] = (unsigned)__half_as_ushort(__float2half(v.x)) |
                 ((unsigned)__half_as_ushort(__float2half(v.y)) << 16);
    }
}

// ---------------------------------------------------------------------------
// GEMM for layer-1 input gates: G[t][n] = concat(x,time)[t] . Wih1[n] + b.
// (fp32, one-shot before the scan — unchanged, proven)
// ---------------------------------------------------------------------------
#define BM 64
#define BN 64
#define BK 32

__global__ __launch_bounds__(256) void gemm_tn(
    const float* __restrict__ B,
    const float* __restrict__ bias1,
    const float* __restrict__ bias2,
    float* __restrict__ C,
    int M, int N, int K,
    const float* __restrict__ x,
    const float* __restrict__ timev)
{
    __shared__ float As[BK][BM + 4];
    __shared__ float Bs[BK][BN + 4];

    const int tid = threadIdx.x;
    const int mblocks = M / BM;
    const int bm = blockIdx.x % mblocks;
    const int bn = blockIdx.x / mblocks;
    const int t0 = bm * BM;
    const int n0 = bn * BN;

    const int tx = tid & 15;
    const int ty = tid >> 4;

    float acc[4][4] = {{0.f}};

    for (int kc = 0; kc < K; kc += BK) {
#pragma unroll
        for (int i = 0; i < 8; i++) {
            int idx = tid + i * 256;
            int r = idx >> 5;
            int c = idx & 31;
            int col = kc + c;
            int trow = t0 + r;
            float av = (col < INDIM) ? x[(size_t)trow * INDIM + col]
                                     : ((col == INDIM) ? timev[trow] : 0.f);
            As[c][r] = av;
            int nrow = n0 + r;
            Bs[c][r] = (col < K) ? B[(size_t)nrow * K + col] : 0.f;
        }
        __syncthreads();

#pragma unroll
        for (int kk = 0; kk < BK; kk++) {
            float a[4], b[4];
#pragma unroll
            for (int i = 0; i < 4; i++) a[i] = As[kk][ty * 4 + i];
#pragma unroll
            for (int j = 0; j < 4; j++) b[j] = Bs[kk][tx * 4 + j];
#pragma unroll
            for (int i = 0; i < 4; i++)
#pragma unroll
                for (int j = 0; j < 4; j++)
                    acc[i][j] = fmaf(a[i], b[j], acc[i][j]);
        }
        __syncthreads();
    }

#pragma unroll
    for (int i = 0; i < 4; i++) {
        int trow = t0 + ty * 4 + i;
#pragma unroll
        for (int j = 0; j < 4; j++) {
            int n = n0 + tx * 4 + j;
            C[(size_t)trow * N + n] = acc[i][j] + bias1[n] + bias2[n];
        }
    }
}

// ---------------------------------------------------------------------------
// Fused dataflow 3-layer scan (R11 structure).
// L1 (wg<64): 16 units/WG, wave q owns unit u0+q, all 4 gates.
// L23: 8 units/WG, wave q owns unit u0+(q>>1), gate pair q&1, serving BOTH
//      layer 2 and layer 3 (shared weights).
// Weight layout (packed f16 pairs): row-major, 512 uints/row; uint j = cols
// (2j, 2j+1). Lane s wants cols (2s+128m, 2s+128m+1) -> uint index s + 64m.
// h rows stay fp32 end-to-end (LDS staged); the poll IS the data load.
// ---------------------------------------------------------------------------
__global__ __launch_bounds__(1024, 4) void fused_scan(
    const unsigned* __restrict__ Wp1,     // packed Whh1, 4096 x 512
    const float* __restrict__ G1,
    const unsigned* __restrict__ Wpi2,    // packed Wih2
    const unsigned* __restrict__ Wph2,    // packed Whh2
    const float* bih2, const float* bhh2,
    const float* h0_1, const float* c0_1,
    const float* h0_2, const float* c0_2,
    const float* h0_3, const float* c0_3,
    float* H1, float* H2, float* H3)
{
    __shared__ float hs1[HDIM];
    __shared__ float hs2[HDIM];
    __shared__ float hs3[HDIM];
    __shared__ float gbuf[16][4];  // L1: [unit 0..15][gate]; L23: 0-7 L2, 8-15 L3

    const int tid = threadIdx.x;
    const int wg  = blockIdx.x;
    const int q   = tid >> 6;      // wave 0..15
    const int s   = tid & 63;

    if (wg < NWG_L1) {
        // ------- Layer 1: WG owns 16 units, wave q owns unit u0+q -------
        const int u0 = wg << 4;
        const int u  = u0 + q;
        unsigned w[4][8];
#pragma unroll
        for (int g = 0; g < 4; ++g) {
            const unsigned* row = Wp1 + (size_t)((g << 10) + u) * 512 + s;
#pragma unroll
            for (int m = 0; m < 8; ++m)
                w[g][m] = row[64 * m];
        }
        float c1 = (tid < 16) ? c0_1[u0 + tid] : 0.f;

        for (int t = 0; t < TSTEPS; ++t) {
            // keep the 32 packed weights live in VGPRs (zero instructions)
#pragma unroll
            for (int g = 0; g < 4; ++g)
#pragma unroll
                for (int m = 0; m < 8; ++m) PINU(w[g][m]);

            float Gv0 = 0.f, Gv1 = 0.f, Gv2 = 0.f, Gv3 = 0.f;
            if (tid < 16) {   // prefetch gate inputs (normal cached loads)
                const float* gptr = G1 + (size_t)t * NGATE + u0 + tid;
                Gv0 = gptr[0];
                Gv1 = gptr[1024];
                Gv2 = gptr[2048];
                Gv3 = gptr[3072];
            }
            // stage h1[t-1]: poll the data itself
            if (t == 0) {
                hs1[tid] = h0_1[tid];
            } else {
                const float* p = H1 + (size_t)(t - 1) * HDIM + tid;
                float v = 0.f;
                for (int it = 0; it < SPIN_MAX; ++it) {
                    v = agent_loadf(p);
                    if (__ballot(isp(v)) == 0ULL) break;
                    __builtin_amdgcn_s_sleep(1);
                }
                hs1[tid] = v;
            }
            __syncthreads();                                   // A: staged

            float a0 = 0.f, a1 = 0.f, a2 = 0.f, a3 = 0.f;
#pragma unroll
            for (int m = 0; m < 8; ++m) {
                float2 hv = *(const float2*)&hs1[2 * s + 128 * m];
                a0 = mix2(hv, w[0][m], a0);
                a1 = mix2(hv, w[1][m], a1);
                a2 = mix2(hv, w[2][m], a2);
                a3 = mix2(hv, w[3][m], a3);
            }
            float s0 = wave_sum64_dpp(a0);
            float s1 = wave_sum64_dpp(a1);
            float s2 = wave_sum64_dpp(a2);
            float s3 = wave_sum64_dpp(a3);
            if (s == 63) {
                gbuf[q][0] = s0;
                gbuf[q][1] = s1;
                gbuf[q][2] = s2;
                gbuf[q][3] = s3;
            }
            __syncthreads();                                   // B: sums ready

            if (tid < 16) {
                float gi = gbuf[tid][0] + Gv0;
                float gf = gbuf[tid][1] + Gv1;
                float gg = gbuf[tid][2] + Gv2;
                float go = gbuf[tid][3] + Gv3;
                float i_ = sigm(gi), f_ = sigm(gf), g_ = fast_tanh(gg), o_ = sigm(go);
                c1 = f_ * c1 + i_ * g_;
                float hn = o_ * fast_tanh(c1);
                agent_storef(H1 + (size_t)t * HDIM + u0 + tid, hn);
            }
            // no drain, no flag: the stored dwords ARE the signal
        }
    } else {
        // ---- Layers 2 & 3 (shared weights): WG owns 8 units ----
        const int ul = q >> 1;     // unit-local 0..7
        const int gp = q & 1;      // 0 -> gates (i,f), 1 -> gates (g,o)
        const int u0 = (wg - NWG_L1) << 3;
        const int u  = u0 + ul;
        unsigned wi[2][8], wh[2][8];
#pragma unroll
        for (int j = 0; j < 2; ++j) {
            const unsigned* ri = Wpi2 + (size_t)(((2 * gp + j) << 10) + u) * 512 + s;
            const unsigned* rh = Wph2 + (size_t)(((2 * gp + j) << 10) + u) * 512 + s;
#pragma unroll
            for (int m = 0; m < 8; ++m) {
                wi[j][m] = ri[64 * m];
                wh[j][m] = rh[64 * m];
            }
        }
        float bias0 = 0.f, bias1v = 0.f, bias2v = 0.f, bias3 = 0.f, cst = 0.f;
        if (tid < 16) {
            int uu = u0 + (tid & 7);
            bias0  = bih2[uu]        + bhh2[uu];
            bias1v = bih2[1024 + uu] + bhh2[1024 + uu];
            bias2v = bih2[2048 + uu] + bhh2[2048 + uu];
            bias3  = bih2[3072 + uu] + bhh2[3072 + uu];
            cst = (tid < 8) ? c0_2[u0 + tid] : c0_3[u0 + tid - 8];
        }

        // iteration t: layer2 tick t (needs h1[t], h2[t-1]) and
        //              layer3 tick t-1 (needs h2[t-1], h3[t-2])
        for (int t = 0; t <= TSTEPS; ++t) {
            // keep the 32 packed weights live in VGPRs (zero instructions)
#pragma unroll
            for (int j = 0; j < 2; ++j)
#pragma unroll
                for (int m = 0; m < 8; ++m) { PINU(wi[j][m]); PINU(wh[j][m]); }

            const bool do2 = (t < TSTEPS);
            const bool do3 = (t >= 1);

            // ---- ONE combined spin loop for all three rows (R15 change) ----
            const bool n1 = do2;       // h1[t]
            const bool n2 = (t > 0);   // h2[t-1]   (t==0 -> h0_2)
            const bool n3 = (t > 1);   // h3[t-2]   (t==1 -> h0_3)
            {
                const float* p1 = H1 + (size_t)t * HDIM + tid;
                const float* p2 = H2 + (size_t)(t - 1) * HDIM + tid;
                const float* p3 = H3 + (size_t)(t - 2) * HDIM + tid;
                float v1 = 0.f, v2 = 0.f, v3 = 0.f;
                for (int it = 0; it < SPIN_MAX; ++it) {
                    if (n1) v1 = agent_loadf(p1);
                    if (n2) v2 = agent_loadf(p2);
                    if (n3) v3 = agent_loadf(p3);
                    bool bad = (n1 && isp(v1)) || (n2 && isp(v2)) || (n3 && isp(v3));
                    if (__ballot(bad) == 0ULL) break;
                    __builtin_amdgcn_s_sleep(1);
                }
                hs1[tid] = v1;
                hs2[tid] = (t == 0) ? h0_2[tid] : v2;
                hs3[tid] = (t == 1) ? h0_3[tid] : v3;
            }
            __syncthreads();                                   // A: staged

            // unconditional dots; inactive-edge garbage discarded at update.
            float p20 = 0.f, p21 = 0.f, p30 = 0.f, p31 = 0.f;
#pragma unroll
            for (int m = 0; m < 8; ++m) {
                float2 h1v = *(const float2*)&hs1[2 * s + 128 * m];
                float2 h2v = *(const float2*)&hs2[2 * s + 128 * m];
                float2 h3v = *(const float2*)&hs3[2 * s + 128 * m];
                p20 = mix2(h1v, wi[0][m], p20);
                p20 = mix2(h2v, wh[0][m], p20);
                p21 = mix2(h1v, wi[1][m], p21);
                p21 = mix2(h2v, wh[1][m], p21);
                p30 = mix2(h2v, wi[0][m], p30);
                p30 = mix2(h3v, wh[0][m], p30);
                p31 = mix2(h2v, wi[1][m], p31);
                p31 = mix2(h3v, wh[1][m], p31);
            }
            float s20 = wave_sum64_dpp(p20);
            float s21 = wave_sum64_dpp(p21);
            float s30 = wave_sum64_dpp(p30);
            float s31 = wave_sum64_dpp(p31);
            if (s == 63) {
                gbuf[ul][2 * gp]          = s20;
                gbuf[ul][2 * gp + 1]      = s21;
                gbuf[8 + ul][2 * gp]      = s30;
                gbuf[8 + ul][2 * gp + 1]  = s31;
            }
            __syncthreads();                                   // B: sums ready

            if (tid < 16) {
                const bool act = (tid < 8) ? do2 : do3;
                if (act) {
                    float gi = gbuf[tid][0] + bias0;
                    float gf = gbuf[tid][1] + bias1v;
                    float gg = gbuf[tid][2] + bias2v;
                    float go = gbuf[tid][3] + bias3;
                    float i_ = sigm(gi), f_ = sigm(gf), g_ = fast_tanh(gg), o_ = sigm(go);
                    cst = f_ * cst + i_ * g_;
                    float hn = o_ * fast_tanh(cst);
                    float* dst = (tid < 8)
                        ? (H2 + (size_t)t * HDIM + u0 + tid)
                        : (H3 + (size_t)(t - 1) * HDIM + u0 + (tid - 8));
                    agent_storef(dst, hn);
                }
            }
        }
    }
}

// ---------------------------------------------------------------------------
// Attention (unchanged, proven)
// ---------------------------------------------------------------------------
__global__ __launch_bounds__(256) void attn_dot(
    const float* __restrict__ H3, float* __restrict__ attn)
{
    const int t = blockIdx.x * 4 + (threadIdx.x >> 6);
    const int lane = threadIdx.x & 63;
    const float* hrow = H3 + (size_t)t * HDIM;
    const float* hf = H3 + (size_t)(TSTEPS - 1) * HDIM;
    float p = 0.f;
    for (int j = lane; j < HDIM; j += 64) p = fmaf(hrow[j], hf[j], p);
#pragma unroll
    for (int d = 32; d; d >>= 1) p += __shfl_down(p, d, 64);
    if (lane == 0) attn[t] = p;
}

__global__ __launch_bounds__(64) void softmax_1024(float* attn)
{
    const int lane = threadIdx.x;
    float vals[16];
    float m = -1e30f;
#pragma unroll
    for (int i = 0; i < 16; i++) {
        vals[i] = attn[lane + i * 64];
        m = fmaxf(m, vals[i]);
    }
#pragma unroll
    for (int d = 32; d; d >>= 1) m = fmaxf(m, __shfl_xor(m, d, 64));
    float s = 0.f;
#pragma unroll
    for (int i = 0; i < 16; i++) {
        vals[i] = expf(vals[i] - m);
        s += vals[i];
    }
#pragma unroll
    for (int d = 32; d; d >>= 1) s += __shfl_xor(s, d, 64);
    float inv = 1.f / s;
#pragma unroll
    for (int i = 0; i < 16; i++) attn[lane + i * 64] = vals[i] * inv;
}

__global__ __launch_bounds__(256) void context_kernel(
    const float* __restrict__ H3, const float* __restrict__ w,
    float* __restrict__ out)
{
    const int u = blockIdx.x * 4 + (threadIdx.x >> 6);
    const int lane = threadIdx.x & 63;
    float p = 0.f;
    for (int t = lane; t < TSTEPS; t += 64)
        p = fmaf(H3[(size_t)t * HDIM + u], w[t], p);
#pragma unroll
    for (int d = 32; d; d >>= 1) p += __shfl_down(p, d, 64);
    if (lane == 0) out[u] = p;
}

// ---------------------------------------------------------------------------
// Launch
// ---------------------------------------------------------------------------
extern "C" void kernel_launch(void* const* d_in, const int* in_sizes, int n_in,
                              void* d_out, int out_size, void* d_ws, size_t ws_size,
                              hipStream_t stream)
{
    const float* x     = (const float*)d_in[0];
    const float* timev = (const float*)d_in[1];
    const float* h0_1  = (const float*)d_in[2];
    const float* c0_1  = (const float*)d_in[3];
    const float* h0_2  = (const float*)d_in[4];
    const float* c0_2  = (const float*)d_in[5];
    const float* h0_3  = (const float*)d_in[6];
    const float* c0_3  = (const float*)d_in[7];
    const float* Wih1  = (const float*)d_in[8];
    const float* Whh1  = (const float*)d_in[9];
    const float* bih1  = (const float*)d_in[10];
    const float* bhh1  = (const float*)d_in[11];
    const float* Wih2  = (const float*)d_in[12];
    const float* Whh2  = (const float*)d_in[13];
    const float* bih2  = (const float*)d_in[14];
    const float* bhh2  = (const float*)d_in[15];

    // workspace carve (~52 MB)
    float* G    = (float*)d_ws;                          // 1024*4096 fp32
    float* H1   = G + (size_t)TSTEPS * NGATE;            // 1024*1024 fp32
    float* H2   = H1 + (size_t)TSTEPS * HDIM;
    float* H3   = H2 + (size_t)TSTEPS * HDIM;
    float* attn = H3 + (size_t)TSTEPS * HDIM;            // 1024 fp32
    unsigned* Wp1  = (unsigned*)(attn + 1024);           // 4096*512 uints each
    unsigned* Wpi2 = Wp1 + (size_t)NGATE * 512;
    unsigned* Wph2 = Wpi2 + (size_t)NGATE * 512;
    float* out  = (float*)d_out;

    // Poison H1..H3 (contiguous): the data-poll protocol depends on it.
    hipMemsetAsync(H1, 0x7C, (size_t)3 * TSTEPS * HDIM * sizeof(float), stream);

    // Pack the three scan weight matrices to f16 pairs (one-time).
    {
        const int n = NGATE * 512;
        pack_f16<<<dim3(n / 256), dim3(256), 0, stream>>>(Whh1, Wp1, n);
        pack_f16<<<dim3(n / 256), dim3(256), 0, stream>>>(Wih2, Wpi2, n);
        pack_f16<<<dim3(n / 256), dim3(256), 0, stream>>>(Whh2, Wph2, n);
    }

    // Layer-1 input gates: G = concat(x,time) @ Wih1^T + bih1 + bhh1 (fp32)
    gemm_tn<<<dim3(1024), dim3(256), 0, stream>>>(Wih1, bih1, bhh1, G,
                                                  TSTEPS, NGATE, INDIM + 1, x, timev);

    // Fused dataflow scan (cooperative: 192 WGs x 1024 threads)
    {
        const unsigned* a0 = Wp1;  const float* a1 = G;
        const unsigned* a2 = Wpi2; const unsigned* a3 = Wph2;
        const float* a4 = bih2;  const float* a5 = bhh2;
        const float* a6 = h0_1;  const float* a7 = c0_1;
        const float* a8 = h0_2;  const float* a9 = c0_2;
        const float* a10 = h0_3; const float* a11 = c0_3;
        float* a12 = H1; float* a13 = H2; float* a14 = H3;
        void* args[] = {&a0,&a1,&a2,&a3,&a4,&a5,&a6,&a7,&a8,&a9,&a10,&a11,
                        &a12,&a13,&a14};
        hipLaunchCooperativeKernel((void*)fused_scan, dim3(NWG_TOT), dim3(1024),
                                   args, 0, stream);
    }

    // Attention
    attn_dot<<<dim3(256), dim3(256), 0, stream>>>(H3, attn);
    softmax_1024<<<dim3(1), dim3(64), 0, stream>>>(attn);
    context_kernel<<<dim3(256), dim3(256), 0, stream>>>(H3, attn, out);
}

// Round 5
// 3686.802 us; speedup vs baseline: 1.4833x; 1.0419x over previous
//
#include <hip/hip_runtime.h>
#include <hip/hip_fp16.h>

// Problem constants
#define TSTEPS 1024
#define HDIM   1024
#define INDIM  512
#define NGATE  4096     // 4*HDIM
#define NWG_L1  64
#define NWG_L23 128
#define NWG_TOT 192     // proven coop envelope
#define POISON_U 0x7C7C7C7Cu   // ~5.2e36 as f32: unreachable for |h|<1 or gate sums
#define SPIN_MAX (1 << 20)     // deadlock valve: fail loud, never hang

// ---------------------------------------------------------------------------
// R15 post-mortem: passed, 3841us (best). FETCH_SIZE 156MB = 152KB/step vs
// ~28KB/step of real data -> the poll protocol re-fetches the hot h rows ~12x
// per step (192 WGs x 1024 lanes reload EVERY lane EVERY spin iteration).
// The retry storm congests the lines it waits on (one cold dispatch hit
// 24.7ms / 204MB -- same mechanism, pathological end).
// R16: PREDICATED RE-POLL -- lanes holding valid data stop reloading; only
// poisoned lanes re-issue. Retry traffic drops ~10x; catch latency converges
// to ~1 HBM RT. Everything else byte-identical to R15.
// ---------------------------------------------------------------------------

typedef _Float16 half2v __attribute__((ext_vector_type(2)));

#define PINU(v) asm volatile("" : "+v"(v))

// fp32 h x packed-f16 weight pair; backend folds fpext+fma into v_fma_mix.
__device__ __forceinline__ float mix2(float2 h, unsigned w, float c) {
    half2v ww = __builtin_bit_cast(half2v, w);
    c = fmaf(h.x, (float)ww[0], c);
    c = fmaf(h.y, (float)ww[1], c);
    return c;
}

// Full-wave sum via DPP adds (VALU pipe; validated R14/R15). Result valid in
// lane 63. row_shr 1,2,4,8 then row_bcast15 (rows 1,3) + row_bcast31 (rows 2,3).
__device__ __forceinline__ float wave_sum64_dpp(float v) {
    int x;
    x = __builtin_amdgcn_update_dpp(0, __float_as_int(v), 0x111, 0xf, 0xf, false); v += __int_as_float(x);
    x = __builtin_amdgcn_update_dpp(0, __float_as_int(v), 0x112, 0xf, 0xf, false); v += __int_as_float(x);
    x = __builtin_amdgcn_update_dpp(0, __float_as_int(v), 0x114, 0xf, 0xf, false); v += __int_as_float(x);
    x = __builtin_amdgcn_update_dpp(0, __float_as_int(v), 0x118, 0xf, 0xf, false); v += __int_as_float(x);
    x = __builtin_amdgcn_update_dpp(0, __float_as_int(v), 0x142, 0xa, 0xf, false); v += __int_as_float(x);
    x = __builtin_amdgcn_update_dpp(0, __float_as_int(v), 0x143, 0xc, 0xf, false); v += __int_as_float(x);
    return v;
}

__device__ __forceinline__ float sigm(float x) { return 1.f / (1.f + __expf(-x)); }
__device__ __forceinline__ float fast_tanh(float x) {
    float t = __expf(-2.f * fabsf(x));
    float r = (1.f - t) / (1.f + t);
    return copysignf(r, x);
}

__device__ __forceinline__ float agent_loadf(const float* p) {
    return __hip_atomic_load(const_cast<float*>(p), __ATOMIC_RELAXED,
                             __HIP_MEMORY_SCOPE_AGENT);
}
__device__ __forceinline__ void agent_storef(float* p, float v) {
    __hip_atomic_store(p, v, __ATOMIC_RELAXED, __HIP_MEMORY_SCOPE_AGENT);
}
__device__ __forceinline__ bool isp(float v) { return __float_as_uint(v) == POISON_U; }

// ---------------------------------------------------------------------------
// Prep: pack fp32 matrix (rows x 1024) into f16-pair uints (rows x 512), RNE.
// dst[i] = f16(col 2i) | f16(col 2i+1)<<16.
// ---------------------------------------------------------------------------
__global__ __launch_bounds__(256) void pack_f16(
    const float* __restrict__ src, unsigned* __restrict__ dst, int n)
{
    int i = blockIdx.x * 256 + threadIdx.x;
    if (i < n) {
        float2 v = *(const float2*)(src + 2 * (size_t)i);
        dst[i] = (unsigned)__half_as_ushort(__float2half(v.x)) |
                 ((unsigned)__half_as_ushort(__float2half(v.y)) << 16);
    }
}

// ---------------------------------------------------------------------------
// GEMM for layer-1 input gates: G[t][n] = concat(x,time)[t] . Wih1[n] + b.
// (fp32, one-shot before the scan — unchanged, proven)
// ---------------------------------------------------------------------------
#define BM 64
#define BN 64
#define BK 32

__global__ __launch_bounds__(256) void gemm_tn(
    const float* __restrict__ B,
    const float* __restrict__ bias1,
    const float* __restrict__ bias2,
    float* __restrict__ C,
    int M, int N, int K,
    const float* __restrict__ x,
    const float* __restrict__ timev)
{
    __shared__ float As[BK][BM + 4];
    __shared__ float Bs[BK][BN + 4];

    const int tid = threadIdx.x;
    const int mblocks = M / BM;
    const int bm = blockIdx.x % mblocks;
    const int bn = blockIdx.x / mblocks;
    const int t0 = bm * BM;
    const int n0 = bn * BN;

    const int tx = tid & 15;
    const int ty = tid >> 4;

    float acc[4][4] = {{0.f}};

    for (int kc = 0; kc < K; kc += BK) {
#pragma unroll
        for (int i = 0; i < 8; i++) {
            int idx = tid + i * 256;
            int r = idx >> 5;
            int c = idx & 31;
            int col = kc + c;
            int trow = t0 + r;
            float av = (col < INDIM) ? x[(size_t)trow * INDIM + col]
                                     : ((col == INDIM) ? timev[trow] : 0.f);
            As[c][r] = av;
            int nrow = n0 + r;
            Bs[c][r] = (col < K) ? B[(size_t)nrow * K + col] : 0.f;
        }
        __syncthreads();

#pragma unroll
        for (int kk = 0; kk < BK; kk++) {
            float a[4], b[4];
#pragma unroll
            for (int i = 0; i < 4; i++) a[i] = As[kk][ty * 4 + i];
#pragma unroll
            for (int j = 0; j < 4; j++) b[j] = Bs[kk][tx * 4 + j];
#pragma unroll
            for (int i = 0; i < 4; i++)
#pragma unroll
                for (int j = 0; j < 4; j++)
                    acc[i][j] = fmaf(a[i], b[j], acc[i][j]);
        }
        __syncthreads();
    }

#pragma unroll
    for (int i = 0; i < 4; i++) {
        int trow = t0 + ty * 4 + i;
#pragma unroll
        for (int j = 0; j < 4; j++) {
            int n = n0 + tx * 4 + j;
            C[(size_t)trow * N + n] = acc[i][j] + bias1[n] + bias2[n];
        }
    }
}

// ---------------------------------------------------------------------------
// Fused dataflow 3-layer scan (R11/R15 structure).
// L1 (wg<64): 16 units/WG, wave q owns unit u0+q, all 4 gates.
// L23: 8 units/WG, wave q owns unit u0+(q>>1), gate pair q&1, serving BOTH
//      layer 2 and layer 3 (shared weights).
// Weight layout (packed f16 pairs): row-major, 512 uints/row; uint j = cols
// (2j, 2j+1). Lane s wants cols (2s+128m, 2s+128m+1) -> uint index s + 64m.
// h rows stay fp32 end-to-end (LDS staged); the poll IS the data load.
// R16: predicated re-poll (only poisoned lanes reload).
// ---------------------------------------------------------------------------
__global__ __launch_bounds__(1024, 4) void fused_scan(
    const unsigned* __restrict__ Wp1,     // packed Whh1, 4096 x 512
    const float* __restrict__ G1,
    const unsigned* __restrict__ Wpi2,    // packed Wih2
    const unsigned* __restrict__ Wph2,    // packed Whh2
    const float* bih2, const float* bhh2,
    const float* h0_1, const float* c0_1,
    const float* h0_2, const float* c0_2,
    const float* h0_3, const float* c0_3,
    float* H1, float* H2, float* H3)
{
    __shared__ float hs1[HDIM];
    __shared__ float hs2[HDIM];
    __shared__ float hs3[HDIM];
    __shared__ float gbuf[16][4];  // L1: [unit 0..15][gate]; L23: 0-7 L2, 8-15 L3

    const int tid = threadIdx.x;
    const int wg  = blockIdx.x;
    const int q   = tid >> 6;      // wave 0..15
    const int s   = tid & 63;

    if (wg < NWG_L1) {
        // ------- Layer 1: WG owns 16 units, wave q owns unit u0+q -------
        const int u0 = wg << 4;
        const int u  = u0 + q;
        unsigned w[4][8];
#pragma unroll
        for (int g = 0; g < 4; ++g) {
            const unsigned* row = Wp1 + (size_t)((g << 10) + u) * 512 + s;
#pragma unroll
            for (int m = 0; m < 8; ++m)
                w[g][m] = row[64 * m];
        }
        float c1 = (tid < 16) ? c0_1[u0 + tid] : 0.f;

        for (int t = 0; t < TSTEPS; ++t) {
            // keep the 32 packed weights live in VGPRs (zero instructions)
#pragma unroll
            for (int g = 0; g < 4; ++g)
#pragma unroll
                for (int m = 0; m < 8; ++m) PINU(w[g][m]);

            float Gv0 = 0.f, Gv1 = 0.f, Gv2 = 0.f, Gv3 = 0.f;
            if (tid < 16) {   // prefetch gate inputs (normal cached loads)
                const float* gptr = G1 + (size_t)t * NGATE + u0 + tid;
                Gv0 = gptr[0];
                Gv1 = gptr[1024];
                Gv2 = gptr[2048];
                Gv3 = gptr[3072];
            }
            // stage h1[t-1]: poll the data itself (predicated re-poll)
            if (t == 0) {
                hs1[tid] = h0_1[tid];
            } else {
                const float* p = H1 + (size_t)(t - 1) * HDIM + tid;
                float v = agent_loadf(p);
                for (int it = 0; it < SPIN_MAX; ++it) {
                    if (__ballot(isp(v)) == 0ULL) break;
                    __builtin_amdgcn_s_sleep(1);
                    if (isp(v)) v = agent_loadf(p);   // only missing lanes reload
                }
                hs1[tid] = v;
            }
            __syncthreads();                                   // A: staged

            float a0 = 0.f, a1 = 0.f, a2 = 0.f, a3 = 0.f;
#pragma unroll
            for (int m = 0; m < 8; ++m) {
                float2 hv = *(const float2*)&hs1[2 * s + 128 * m];
                a0 = mix2(hv, w[0][m], a0);
                a1 = mix2(hv, w[1][m], a1);
                a2 = mix2(hv, w[2][m], a2);
                a3 = mix2(hv, w[3][m], a3);
            }
            float s0 = wave_sum64_dpp(a0);
            float s1 = wave_sum64_dpp(a1);
            float s2 = wave_sum64_dpp(a2);
            float s3 = wave_sum64_dpp(a3);
            if (s == 63) {
                gbuf[q][0] = s0;
                gbuf[q][1] = s1;
                gbuf[q][2] = s2;
                gbuf[q][3] = s3;
            }
            __syncthreads();                                   // B: sums ready

            if (tid < 16) {
                float gi = gbuf[tid][0] + Gv0;
                float gf = gbuf[tid][1] + Gv1;
                float gg = gbuf[tid][2] + Gv2;
                float go = gbuf[tid][3] + Gv3;
                float i_ = sigm(gi), f_ = sigm(gf), g_ = fast_tanh(gg), o_ = sigm(go);
                c1 = f_ * c1 + i_ * g_;
                float hn = o_ * fast_tanh(c1);
                agent_storef(H1 + (size_t)t * HDIM + u0 + tid, hn);
            }
            // no drain, no flag: the stored dwords ARE the signal
        }
    } else {
        // ---- Layers 2 & 3 (shared weights): WG owns 8 units ----
        const int ul = q >> 1;     // unit-local 0..7
        const int gp = q & 1;      // 0 -> gates (i,f), 1 -> gates (g,o)
        const int u0 = (wg - NWG_L1) << 3;
        const int u  = u0 + ul;
        unsigned wi[2][8], wh[2][8];
#pragma unroll
        for (int j = 0; j < 2; ++j) {
            const unsigned* ri = Wpi2 + (size_t)(((2 * gp + j) << 10) + u) * 512 + s;
            const unsigned* rh = Wph2 + (size_t)(((2 * gp + j) << 10) + u) * 512 + s;
#pragma unroll
            for (int m = 0; m < 8; ++m) {
                wi[j][m] = ri[64 * m];
                wh[j][m] = rh[64 * m];
            }
        }
        float bias0 = 0.f, bias1v = 0.f, bias2v = 0.f, bias3 = 0.f, cst = 0.f;
        if (tid < 16) {
            int uu = u0 + (tid & 7);
            bias0  = bih2[uu]        + bhh2[uu];
            bias1v = bih2[1024 + uu] + bhh2[1024 + uu];
            bias2v = bih2[2048 + uu] + bhh2[2048 + uu];
            bias3  = bih2[3072 + uu] + bhh2[3072 + uu];
            cst = (tid < 8) ? c0_2[u0 + tid] : c0_3[u0 + tid - 8];
        }

        // iteration t: layer2 tick t (needs h1[t], h2[t-1]) and
        //              layer3 tick t-1 (needs h2[t-1], h3[t-2])
        for (int t = 0; t <= TSTEPS; ++t) {
            // keep the 32 packed weights live in VGPRs (zero instructions)
#pragma unroll
            for (int j = 0; j < 2; ++j)
#pragma unroll
                for (int m = 0; m < 8; ++m) { PINU(wi[j][m]); PINU(wh[j][m]); }

            const bool do2 = (t < TSTEPS);
            const bool do3 = (t >= 1);

            // ---- ONE combined spin loop, predicated re-poll (R16) ----
            const bool n1 = do2;       // h1[t]
            const bool n2 = (t > 0);   // h2[t-1]   (t==0 -> h0_2)
            const bool n3 = (t > 1);   // h3[t-2]   (t==1 -> h0_3)
            {
                const float* p1 = H1 + (size_t)t * HDIM + tid;
                const float* p2 = H2 + (size_t)(t - 1) * HDIM + tid;
                const float* p3 = H3 + (size_t)(t - 2) * HDIM + tid;
                float v1 = 0.f, v2 = 0.f, v3 = 0.f;
                if (n1) v1 = agent_loadf(p1);
                if (n2) v2 = agent_loadf(p2);
                if (n3) v3 = agent_loadf(p3);
                for (int it = 0; it < SPIN_MAX; ++it) {
                    bool bad = (n1 && isp(v1)) || (n2 && isp(v2)) || (n3 && isp(v3));
                    if (__ballot(bad) == 0ULL) break;
                    __builtin_amdgcn_s_sleep(1);
                    if (n1 && isp(v1)) v1 = agent_loadf(p1);   // only missing
                    if (n2 && isp(v2)) v2 = agent_loadf(p2);   // lanes reload
                    if (n3 && isp(v3)) v3 = agent_loadf(p3);
                }
                hs1[tid] = v1;
                hs2[tid] = (t == 0) ? h0_2[tid] : v2;
                hs3[tid] = (t == 1) ? h0_3[tid] : v3;
            }
            __syncthreads();                                   // A: staged

            // unconditional dots; inactive-edge garbage discarded at update.
            float p20 = 0.f, p21 = 0.f, p30 = 0.f, p31 = 0.f;
#pragma unroll
            for (int m = 0; m < 8; ++m) {
                float2 h1v = *(const float2*)&hs1[2 * s + 128 * m];
                float2 h2v = *(const float2*)&hs2[2 * s + 128 * m];
                float2 h3v = *(const float2*)&hs3[2 * s + 128 * m];
                p20 = mix2(h1v, wi[0][m], p20);
                p20 = mix2(h2v, wh[0][m], p20);
                p21 = mix2(h1v, wi[1][m], p21);
                p21 = mix2(h2v, wh[1][m], p21);
                p30 = mix2(h2v, wi[0][m], p30);
                p30 = mix2(h3v, wh[0][m], p30);
                p31 = mix2(h2v, wi[1][m], p31);
                p31 = mix2(h3v, wh[1][m], p31);
            }
            float s20 = wave_sum64_dpp(p20);
            float s21 = wave_sum64_dpp(p21);
            float s30 = wave_sum64_dpp(p30);
            float s31 = wave_sum64_dpp(p31);
            if (s == 63) {
                gbuf[ul][2 * gp]          = s20;
                gbuf[ul][2 * gp + 1]      = s21;
                gbuf[8 + ul][2 * gp]      = s30;
                gbuf[8 + ul][2 * gp + 1]  = s31;
            }
            __syncthreads();                                   // B: sums ready

            if (tid < 16) {
                const bool act = (tid < 8) ? do2 : do3;
                if (act) {
                    float gi = gbuf[tid][0] + bias0;
                    float gf = gbuf[tid][1] + bias1v;
                    float gg = gbuf[tid][2] + bias2v;
                    float go = gbuf[tid][3] + bias3;
                    float i_ = sigm(gi), f_ = sigm(gf), g_ = fast_tanh(gg), o_ = sigm(go);
                    cst = f_ * cst + i_ * g_;
                    float hn = o_ * fast_tanh(cst);
                    float* dst = (tid < 8)
                        ? (H2 + (size_t)t * HDIM + u0 + tid)
                        : (H3 + (size_t)(t - 1) * HDIM + u0 + (tid - 8));
                    agent_storef(dst, hn);
                }
            }
        }
    }
}

// ---------------------------------------------------------------------------
// Attention (unchanged, proven)
// ---------------------------------------------------------------------------
__global__ __launch_bounds__(256) void attn_dot(
    const float* __restrict__ H3, float* __restrict__ attn)
{
    const int t = blockIdx.x * 4 + (threadIdx.x >> 6);
    const int lane = threadIdx.x & 63;
    const float* hrow = H3 + (size_t)t * HDIM;
    const float* hf = H3 + (size_t)(TSTEPS - 1) * HDIM;
    float p = 0.f;
    for (int j = lane; j < HDIM; j += 64) p = fmaf(hrow[j], hf[j], p);
#pragma unroll
    for (int d = 32; d; d >>= 1) p += __shfl_down(p, d, 64);
    if (lane == 0) attn[t] = p;
}

__global__ __launch_bounds__(64) void softmax_1024(float* attn)
{
    const int lane = threadIdx.x;
    float vals[16];
    float m = -1e30f;
#pragma unroll
    for (int i = 0; i < 16; i++) {
        vals[i] = attn[lane + i * 64];
        m = fmaxf(m, vals[i]);
    }
#pragma unroll
    for (int d = 32; d; d >>= 1) m = fmaxf(m, __shfl_xor(m, d, 64));
    float s = 0.f;
#pragma unroll
    for (int i = 0; i < 16; i++) {
        vals[i] = expf(vals[i] - m);
        s += vals[i];
    }
#pragma unroll
    for (int d = 32; d; d >>= 1) s += __shfl_xor(s, d, 64);
    float inv = 1.f / s;
#pragma unroll
    for (int i = 0; i < 16; i++) attn[lane + i * 64] = vals[i] * inv;
}

__global__ __launch_bounds__(256) void context_kernel(
    const float* __restrict__ H3, const float* __restrict__ w,
    float* __restrict__ out)
{
    const int u = blockIdx.x * 4 + (threadIdx.x >> 6);
    const int lane = threadIdx.x & 63;
    float p = 0.f;
    for (int t = lane; t < TSTEPS; t += 64)
        p = fmaf(H3[(size_t)t * HDIM + u], w[t], p);
#pragma unroll
    for (int d = 32; d; d >>= 1) p += __shfl_down(p, d, 64);
    if (lane == 0) out[u] = p;
}

// ---------------------------------------------------------------------------
// Launch
// ---------------------------------------------------------------------------
extern "C" void kernel_launch(void* const* d_in, const int* in_sizes, int n_in,
                              void* d_out, int out_size, void* d_ws, size_t ws_size,
                              hipStream_t stream)
{
    const float* x     = (const float*)d_in[0];
    const float* timev = (const float*)d_in[1];
    const float* h0_1  = (const float*)d_in[2];
    const float* c0_1  = (const float*)d_in[3];
    const float* h0_2  = (const float*)d_in[4];
    const float* c0_2  = (const float*)d_in[5];
    const float* h0_3  = (const float*)d_in[6];
    const float* c0_3  = (const float*)d_in[7];
    const float* Wih1  = (const float*)d_in[8];
    const float* Whh1  = (const float*)d_in[9];
    const float* bih1  = (const float*)d_in[10];
    const float* bhh1  = (const float*)d_in[11];
    const float* Wih2  = (const float*)d_in[12];
    const float* Whh2  = (const float*)d_in[13];
    const float* bih2  = (const float*)d_in[14];
    const float* bhh2  = (const float*)d_in[15];

    // workspace carve (~52 MB)
    float* G    = (float*)d_ws;                          // 1024*4096 fp32
    float* H1   = G + (size_t)TSTEPS * NGATE;            // 1024*1024 fp32
    float* H2   = H1 + (size_t)TSTEPS * HDIM;
    float* H3   = H2 + (size_t)TSTEPS * HDIM;
    float* attn = H3 + (size_t)TSTEPS * HDIM;            // 1024 fp32
    unsigned* Wp1  = (unsigned*)(attn + 1024);           // 4096*512 uints each
    unsigned* Wpi2 = Wp1 + (size_t)NGATE * 512;
    unsigned* Wph2 = Wpi2 + (size_t)NGATE * 512;
    float* out  = (float*)d_out;

    // Poison H1..H3 (contiguous): the data-poll protocol depends on it.
    hipMemsetAsync(H1, 0x7C, (size_t)3 * TSTEPS * HDIM * sizeof(float), stream);

    // Pack the three scan weight matrices to f16 pairs (one-time).
    {
        const int n = NGATE * 512;
        pack_f16<<<dim3(n / 256), dim3(256), 0, stream>>>(Whh1, Wp1, n);
        pack_f16<<<dim3(n / 256), dim3(256), 0, stream>>>(Wih2, Wpi2, n);
        pack_f16<<<dim3(n / 256), dim3(256), 0, stream>>>(Whh2, Wph2, n);
    }

    // Layer-1 input gates: G = concat(x,time) @ Wih1^T + bih1 + bhh1 (fp32)
    gemm_tn<<<dim3(1024), dim3(256), 0, stream>>>(Wih1, bih1, bhh1, G,
                                                  TSTEPS, NGATE, INDIM + 1, x, timev);

    // Fused dataflow scan (cooperative: 192 WGs x 1024 threads)
    {
        const unsigned* a0 = Wp1;  const float* a1 = G;
        const unsigned* a2 = Wpi2; const unsigned* a3 = Wph2;
        const float* a4 = bih2;  const float* a5 = bhh2;
        const float* a6 = h0_1;  const float* a7 = c0_1;
        const float* a8 = h0_2;  const float* a9 = c0_2;
        const float* a10 = h0_3; const float* a11 = c0_3;
        float* a12 = H1; float* a13 = H2; float* a14 = H3;
        void* args[] = {&a0,&a1,&a2,&a3,&a4,&a5,&a6,&a7,&a8,&a9,&a10,&a11,
                        &a12,&a13,&a14};
        hipLaunchCooperativeKernel((void*)fused_scan, dim3(NWG_TOT), dim3(1024),
                                   args, 0, stream);
    }

    // Attention
    attn_dot<<<dim3(256), dim3(256), 0, stream>>>(H3, attn);
    softmax_1024<<<dim3(1), dim3(64), 0, stream>>>(attn);
    context_kernel<<<dim3(256), dim3(256), 0, stream>>>(H3, attn, out);
}